// Round 12
// baseline (240.985 us; speedup 1.0000x reference)
//
#include <hip/hip_runtime.h>
#include <hip/hip_fp16.h>

// Fused MSE + SSIM loss, 32x3x512x512 fp32, MI355X — R15.
// Ledger: R12 = 88.3us proven best (MFMA stage B, pi32 conflict-free LDS, GWPAD).
// All structure/occupancy experiments regressed: R13 (384thr, 105.7), R14
// (42-row LDS + clamp, 92.4 — occupancy did NOT rise with smaller LDS; clamp
// broke immediate-offset ds_reads). Occupancy axis is dead in both directions.
// R15 = R12 byte-identical per-tile + PLANE PAIRING: each block runs the same
// (x,y) tile for 2 consecutive planes (grid 8x16x48 = 6144 blocks).
//   A(0); bar; B(0); bar; A(1); bar; B(1)  — same barrier density per tile;
//   prologue (gwh/afrag/colR) + epilogue (reduce + atomics) + launch overhead
//   paid once per 2 tiles; CU batches 8 -> 4 (half the tails); atomics halved.
// Ending: spread-slot atomics + separate finalize (R7 lesson).

#define WSZ   512
#define TW    64
#define TH    32
#define HALO  5
#define IN_H  (TH + 2*HALO)    // 42 rows of horizontal-pass output
#define BUFR  48               // padded to 48 for MFMA K-tile reads
#define GX    (WSZ / TW)       // 8
#define GY    (WSZ / TH)       // 16
#define PPB   2                // planes per block
#define NSLOT 64
#define SSIM_C1 0.0001f
#define SSIM_C2 0.0009f

// 11-tap gaussian, sigma=1.5, normalized
#define W0 0.00102838f
#define W1 0.00759876f
#define W2 0.03600080f
#define W3 0.10936080f
#define W4 0.21300560f
#define W5 0.26601170f

typedef _Float16 f16x4 __attribute__((ext_vector_type(4)));
typedef float    f32x4 __attribute__((ext_vector_type(4)));

// zero-padded gaussian: GWPAD[16+k] = gw[k], k=0..10
__device__ __constant__ float GWPAD[48] = {
    0,0,0,0,0,0,0,0,0,0,0,0,0,0,0,0,
    W0,W1,W2,W3,W4,W5,W4,W3,W2,W1,W0,
    0,0,0,0,0,0,0,0,0,0,0,0,0,0,0,0,0,0,0,0,0
};

static __device__ __forceinline__ __half2 pk(float a, float b) {
    return __builtin_bit_cast(__half2, __builtin_amdgcn_cvt_pkrtz(a, b));
}
static __device__ __forceinline__ unsigned pku(float a, float b) {
    return __builtin_bit_cast(unsigned, __builtin_amdgcn_cvt_pkrtz(a, b));
}
// staggered pair: (lo.hi, hi.lo) == (x[2u+1], x[2u+2])
static __device__ __forceinline__ __half2 stagger(__half2 hi, __half2 lo) {
    return __builtin_bit_cast(__half2,
        __builtin_amdgcn_alignbit(__builtin_bit_cast(unsigned, hi),
                                  __builtin_bit_cast(unsigned, lo), 16));
}
// bank-disperse permutation on 0..31: out = [b1,b0,b2,b4^b1,b3^b0]
// store (m fixed, q varies): (b2,b3,b4) bijective -> 8 distinct bank-quads.
// read (t-group, p=8n+j): (b0,b1,b2) bijective -> 8 distinct bank-quads.
static __device__ __forceinline__ int pi32(int pos) {
    const int b0 = pos & 1, b1 = (pos >> 1) & 1, b2 = (pos >> 2) & 1;
    const int b3 = (pos >> 3) & 1, b4 = (pos >> 4) & 1;
    return (b1 << 4) | (b0 << 3) | (b2 << 2) | ((b4 ^ b1) << 1) | (b3 ^ b0);
}

__launch_bounds__(256, 6)
__global__ void fused_mse_ssim(const float* __restrict__ P,
                               const float* __restrict__ T,
                               float* __restrict__ ws) {
    __shared__ float4 sAB[BUFR][32];    // fields per slot: S, D, SS, DD (half2)
    __shared__ float  red[2][4];

    const int tid = threadIdx.x;
    const int gx0 = blockIdx.x * TW;
    const int gy0 = blockIdx.y * TH;
    const bool xedge = (blockIdx.x == 0) || (blockIdx.x == GX - 1);

    const float gwf[11] = {W0,W1,W2,W3,W4,W5,W4,W3,W2,W1,W0};
    unsigned gwh[11];   // half2(w,w) bit patterns, wave-uniform -> SGPR
    #pragma unroll
    for (int k = 0; k < 11; ++k)
        gwh[k] = __builtin_amdgcn_readfirstlane(
                     __builtin_bit_cast(unsigned, __float2half2_rn(gwf[k])));

    // ---- hoisted stage-B constants (paid once per PPB tiles) ----
    const int lane = tid & 63;
    const int nT   = tid >> 6;            // N-tile = wave id
    const int t    = lane >> 4;
    const int colL = lane & 15;
    const int x    = (nT << 4) | colL;    // px col 0..63
    const int p    = x >> 1;              // pair index
    const int colR = pi32(p);             // LDS col (row-independent)
    const unsigned sel = (x & 1) ? 0x07060302u : 0x05040100u;

    // weight fragments for K-tile offset c=0,1: constant-table loads + pkrtz
    f16x4 afrag[2];
    #pragma unroll
    for (int c = 0; c < 2; ++c) {
        float av[4];
        #pragma unroll
        for (int i = 0; i < 4; ++i)
            av[i] = GWPAD[16 * c + 4 * t + i - colL + 16];
        uint2 au;
        au.x = pku(av[0], av[1]);
        au.y = pku(av[2], av[3]);
        afrag[c] = __builtin_bit_cast(f16x4, au);
    }

    // zero-fill pad rows 42..47 once (stage A never writes them; weights there
    // are zero but LDS must not hold Inf/NaN garbage)
    if (tid < 192)
        sAB[IN_H + (tid >> 5)][tid & 31] = make_float4(0.f, 0.f, 0.f, 0.f);

    float mse = 0.f;
    float ssim = 0.f;

    for (int pl = 0; pl < PPB; ++pl) {
        const size_t plane = (size_t)(blockIdx.z * PPB + pl) * (WSZ * (size_t)WSZ);
        const float* Pp = P + plane;
        const float* Tp = T + plane;

        // ---- stage A (R12-proven): packed-fp16 horizontal 11-tap ----
        for (int it = tid; it < IN_H * 8; it += 256) {
            const int r  = it >> 3;
            const int q  = it & 7;
            const int gy = gy0 - HALO + r;
            const int cb = gx0 + q * 8 - 8;        // leftmost loaded px (16B aligned)
            const float* prow = Pp + ((long)gy * WSZ + cb);
            const float* trow = Tp + ((long)gy * WSZ + cb);
            const bool rv   = ((unsigned)gy < (unsigned)WSZ);
            const bool mrow = ((unsigned)(r - HALO) < (unsigned)TH);

            const __half2 z = __float2half2_rn(0.f);
            __half2 As[12], Ad[12];

            if (!xedge) {
                if (rv) {
                    #pragma unroll
                    for (int b = 0; b < 6; ++b) {
                        const float4 pv = *(const float4*)(prow + 4 * b);
                        const float4 tv = *(const float4*)(trow + 4 * b);
                        const float s0 = pv.x + tv.x, s1 = pv.y + tv.y;
                        const float s2 = pv.z + tv.z, s3 = pv.w + tv.w;
                        const float d0 = pv.x - tv.x, d1 = pv.y - tv.y;
                        const float d2 = pv.z - tv.z, d3 = pv.w - tv.w;
                        As[2*b]   = pk(s0, s1); As[2*b+1] = pk(s2, s3);
                        Ad[2*b]   = pk(d0, d1); Ad[2*b+1] = pk(d2, d3);
                        if ((b == 2 || b == 3) && mrow) {
                            mse = fmaf(d0, d0, mse); mse = fmaf(d1, d1, mse);
                            mse = fmaf(d2, d2, mse); mse = fmaf(d3, d3, mse);
                        }
                    }
                } else {
                    #pragma unroll
                    for (int b = 0; b < 12; ++b) { As[b] = z; Ad[b] = z; }
                }
            } else {
                #pragma unroll
                for (int b = 0; b < 6; ++b) {
                    const unsigned cc = (unsigned)(cb + 4 * b);
                    float4 pv = make_float4(0.f, 0.f, 0.f, 0.f);
                    float4 tv = make_float4(0.f, 0.f, 0.f, 0.f);
                    if (rv && cc < (unsigned)WSZ) {
                        pv = *(const float4*)(prow + 4 * b);
                        tv = *(const float4*)(trow + 4 * b);
                    }
                    const float s0 = pv.x + tv.x, s1 = pv.y + tv.y;
                    const float s2 = pv.z + tv.z, s3 = pv.w + tv.w;
                    const float d0 = pv.x - tv.x, d1 = pv.y - tv.y;
                    const float d2 = pv.z - tv.z, d3 = pv.w - tv.w;
                    As[2*b]   = pk(s0, s1); As[2*b+1] = pk(s2, s3);
                    Ad[2*b]   = pk(d0, d1); Ad[2*b+1] = pk(d2, d3);
                    if ((b == 2 || b == 3) && mrow) {
                        mse = fmaf(d0, d0, mse); mse = fmaf(d1, d1, mse);
                        mse = fmaf(d2, d2, mse); mse = fmaf(d3, d3, mse);
                    }
                }
            }

            // packed conv: output pair m needs px[3+2m+k], k=0..10
            __half2 aS[4]  = {z, z, z, z};
            __half2 aD[4]  = {z, z, z, z};
            __half2 aSS[4] = {z, z, z, z};
            __half2 aDD[4] = {z, z, z, z};

            #pragma unroll
            for (int jj = 0; jj <= 16; ++jj) {
                const int j = jj + 3;
                __half2 vs, vd;
                if (j & 1) {
                    vs = stagger(As[(j >> 1) + 1], As[j >> 1]);
                    vd = stagger(Ad[(j >> 1) + 1], Ad[j >> 1]);
                } else {
                    vs = As[j >> 1];
                    vd = Ad[j >> 1];
                }
                const __half2 vss = __hmul2(vs, vs);
                const __half2 vdd = __hmul2(vd, vd);
                #pragma unroll
                for (int m = 0; m < 4; ++m) {
                    const int k = jj - 2 * m;
                    if (k >= 0 && k < 11) {
                        const __half2 w = __builtin_bit_cast(__half2, gwh[k]);
                        aS[m]  = __hfma2(w, vs,  aS[m]);
                        aD[m]  = __hfma2(w, vd,  aD[m]);
                        aSS[m] = __hfma2(w, vss, aSS[m]);
                        aDD[m] = __hfma2(w, vdd, aDD[m]);
                    }
                }
            }

            // bank-disperse store: pair pos = 4q+m lives at col pi32(pos)
            #pragma unroll
            for (int m = 0; m < 4; ++m)
                sAB[r][pi32(4 * q + m)] = make_float4(
                    __builtin_bit_cast(float, aS[m]),  __builtin_bit_cast(float, aD[m]),
                    __builtin_bit_cast(float, aSS[m]), __builtin_bit_cast(float, aDD[m]));
        }
        __syncthreads();

        // ---- stage B: vertical 11-tap via MFMA (R12-verified mapping) ----
        f32x4 Dacc[2][4];   // [m][field]
        #pragma unroll
        for (int m = 0; m < 2; ++m)
            #pragma unroll
            for (int f = 0; f < 4; ++f)
                Dacc[m][f] = (f32x4){0.f, 0.f, 0.f, 0.f};

        // 3 distinct K-windows: base 0 (m0c0), 16 (m0c1 = m1c0), 32 (m1c1)
        #pragma unroll
        for (int bi = 0; bi < 3; ++bi) {
            const int base = bi << 4;
            float4 ld[4];
            #pragma unroll
            for (int i = 0; i < 4; ++i)
                ld[i] = sAB[base + 4 * t + i][colR];
            const unsigned* w0 = (const unsigned*)&ld[0];
            const unsigned* w1 = (const unsigned*)&ld[1];
            const unsigned* w2 = (const unsigned*)&ld[2];
            const unsigned* w3 = (const unsigned*)&ld[3];

            f16x4 bf[4];
            #pragma unroll
            for (int f = 0; f < 4; ++f) {
                uint2 bu;
                bu.x = __builtin_amdgcn_perm(w1[f], w0[f], sel);   // k=4t+0,4t+1
                bu.y = __builtin_amdgcn_perm(w3[f], w2[f], sel);   // k=4t+2,4t+3
                bf[f] = __builtin_bit_cast(f16x4, bu);
            }

            if (bi == 0) {
                #pragma unroll
                for (int f = 0; f < 4; ++f)
                    Dacc[0][f] = __builtin_amdgcn_mfma_f32_16x16x16f16(
                                     afrag[0], bf[f], Dacc[0][f], 0, 0, 0);
            } else if (bi == 1) {
                #pragma unroll
                for (int f = 0; f < 4; ++f) {
                    Dacc[0][f] = __builtin_amdgcn_mfma_f32_16x16x16f16(
                                     afrag[1], bf[f], Dacc[0][f], 0, 0, 0);
                    Dacc[1][f] = __builtin_amdgcn_mfma_f32_16x16x16f16(
                                     afrag[0], bf[f], Dacc[1][f], 0, 0, 0);
                }
            } else {
                #pragma unroll
                for (int f = 0; f < 4; ++f)
                    Dacc[1][f] = __builtin_amdgcn_mfma_f32_16x16x16f16(
                                     afrag[1], bf[f], Dacc[1][f], 0, 0, 0);
            }
        }

        // SSIM epilogue (fp32), S/D algebra; 8 px per thread:
        //   2mu12+C1 = 0.5(A^2-B^2)+C1 ; mu1^2+mu2^2+C1 = 0.5(A^2+B^2)+C1
        //   2s12+C2  = 0.5((X-Y)-(A^2-B^2))+C2 ; s1+s2+C2 = 0.5((X+Y)-(A^2+B^2))+C2
        #pragma unroll
        for (int m = 0; m < 2; ++m) {
            #pragma unroll
            for (int j = 0; j < 4; ++j) {
                const float A = Dacc[m][0][j];
                const float B = Dacc[m][1][j];
                const float X = Dacc[m][2][j];
                const float Y = Dacc[m][3][j];
                const float a2 = A * A;
                const float b2 = B * B;
                const float P1 = a2 + b2;
                const float M1 = a2 - b2;
                const float num1 = fmaf(0.5f, M1, SSIM_C1);
                const float den1 = fmaf(0.5f, P1, SSIM_C1);
                const float num2 = fmaf(0.5f, (X - Y) - M1, SSIM_C2);
                const float den2 = fmaf(0.5f, (X + Y) - P1, SSIM_C2);
                ssim = fmaf(num1 * num2, __builtin_amdgcn_rcpf(den1 * den2), ssim);
            }
        }
        __syncthreads();   // LDS reads done before next plane's stage A writes
    }

    // ---- reduction: wave shuffle -> LDS -> 2 plain atomics into a spread slot ----
    #pragma unroll
    for (int off = 32; off > 0; off >>= 1) {
        mse  += __shfl_down(mse, off);
        ssim += __shfl_down(ssim, off);
    }
    const int wid = tid >> 6;
    if ((tid & 63) == 0) { red[0][wid] = mse; red[1][wid] = ssim; }
    __syncthreads();
    if (tid == 0) {
        const float m = red[0][0] + red[0][1] + red[0][2] + red[0][3];
        const float s = red[1][0] + red[1][1] + red[1][2] + red[1][3];
        const int bid  = (blockIdx.z * gridDim.y + blockIdx.y) * gridDim.x + blockIdx.x;
        const int slot = (bid & (NSLOT - 1)) * 16;     // 64B apart -> no line bouncing
        atomicAdd(&ws[slot + 0], m);
        atomicAdd(&ws[slot + 1], s);
    }
}

__global__ void finalize_loss(const float* __restrict__ ws,
                              float* __restrict__ out, float invN) {
    const int t = threadIdx.x;           // 64 threads
    float m = ws[t * 16 + 0];
    float s = ws[t * 16 + 1];
    #pragma unroll
    for (int off = 32; off > 0; off >>= 1) {
        m += __shfl_down(m, off);
        s += __shfl_down(s, off);
    }
    if (t == 0) out[0] = m * invN + 0.01f * (1.f - s * invN);
}

extern "C" void kernel_launch(void* const* d_in, const int* in_sizes, int n_in,
                              void* d_out, int out_size, void* d_ws, size_t ws_size,
                              hipStream_t stream) {
    const float* P = (const float*)d_in[0];
    const float* T = (const float*)d_in[1];
    float* out = (float*)d_out;
    float* ws  = (float*)d_ws;

    const int planes = in_sizes[0] / (WSZ * WSZ);     // 96
    const float invN = 1.f / (float)in_sizes[0];

    (void)hipMemsetAsync(ws, 0, NSLOT * 16 * sizeof(float), stream);
    dim3 grid(GX, GY, planes / PPB);                  // 8 x 16 x 48
    fused_mse_ssim<<<grid, 256, 0, stream>>>(P, T, ws);
    finalize_loss<<<1, 64, 0, stream>>>(ws, out, invN);
}

// Round 13
// 226.896 us; speedup vs baseline: 1.0621x; 1.0621x over previous
//
#include <hip/hip_runtime.h>
#include <hip/hip_fp16.h>

// Fused MSE + SSIM loss, 32x3x512x512 fp32, MI355X — R16 = R12 verbatim (revert
// to proven best, 88.3us). Closing the session on the measured optimum.
// Session ledger: 125 (R4) -> 95.7 (R5 packed-fp16 S/D math) -> 88.3 (R12: MFMA
// vertical pass + pi32 conflict-free LDS + GWPAD afrag). All seven structural
// experiments around this point regressed (R6 235, R8 110, R9 105, R13 106,
// R14 92, R15 104): occupancy, balance, LDS-size, and amortization axes are
// each falsified in both directions. Remaining gap to the 32us HBM floor is
// distributed memory latency this structure cannot trade away.
// Key proven pieces:
//  - S/D algebra: conv {S,D,S^2,D^2}, SSIM from A,B,X,Y; MSE = sum(D^2) free.
//  - Horizontal conv packed fp16 (staggered pairs via v_alignbit).
//  - Vertical conv on MFMA (16x16x16 f16, banded Toeplitz weights from
//    __constant__ GWPAD; fp32 accumulation in C-regs).
//  - pi32 bank-disperse LDS permutation: conflict-free store AND read (0 cnt).
//  - Spread-slot atomics + separate finalize kernel (R7: never per-block
//    device-scope fenced RMW at 24K-block scale).

#define WSZ   512
#define TW    64
#define TH    32
#define HALO  5
#define IN_H  (TH + 2*HALO)    // 42 rows of horizontal-pass output
#define BUFR  48               // padded to 48 for MFMA K-tile reads
#define GX    (WSZ / TW)       // 8
#define GY    (WSZ / TH)       // 16
#define NSLOT 64
#define SSIM_C1 0.0001f
#define SSIM_C2 0.0009f

// 11-tap gaussian, sigma=1.5, normalized
#define W0 0.00102838f
#define W1 0.00759876f
#define W2 0.03600080f
#define W3 0.10936080f
#define W4 0.21300560f
#define W5 0.26601170f

typedef _Float16 f16x4 __attribute__((ext_vector_type(4)));
typedef float    f32x4 __attribute__((ext_vector_type(4)));

// zero-padded gaussian: GWPAD[16+k] = gw[k], k=0..10
__device__ __constant__ float GWPAD[48] = {
    0,0,0,0,0,0,0,0,0,0,0,0,0,0,0,0,
    W0,W1,W2,W3,W4,W5,W4,W3,W2,W1,W0,
    0,0,0,0,0,0,0,0,0,0,0,0,0,0,0,0,0,0,0,0,0
};

static __device__ __forceinline__ __half2 pk(float a, float b) {
    return __builtin_bit_cast(__half2, __builtin_amdgcn_cvt_pkrtz(a, b));
}
static __device__ __forceinline__ unsigned pku(float a, float b) {
    return __builtin_bit_cast(unsigned, __builtin_amdgcn_cvt_pkrtz(a, b));
}
// staggered pair: (lo.hi, hi.lo) == (x[2u+1], x[2u+2])
static __device__ __forceinline__ __half2 stagger(__half2 hi, __half2 lo) {
    return __builtin_bit_cast(__half2,
        __builtin_amdgcn_alignbit(__builtin_bit_cast(unsigned, hi),
                                  __builtin_bit_cast(unsigned, lo), 16));
}
// bank-disperse permutation on 0..31: out = [b1,b0,b2,b4^b1,b3^b0]
// store (m fixed, q varies): (b2,b3,b4) bijective -> 8 distinct bank-quads.
// read (t-group, p=8n+j): (b0,b1,b2) bijective -> 8 distinct bank-quads.
static __device__ __forceinline__ int pi32(int pos) {
    const int b0 = pos & 1, b1 = (pos >> 1) & 1, b2 = (pos >> 2) & 1;
    const int b3 = (pos >> 3) & 1, b4 = (pos >> 4) & 1;
    return (b1 << 4) | (b0 << 3) | (b2 << 2) | ((b4 ^ b1) << 1) | (b3 ^ b0);
}

__launch_bounds__(256, 6)
__global__ void fused_mse_ssim(const float* __restrict__ P,
                               const float* __restrict__ T,
                               float* __restrict__ ws) {
    __shared__ float4 sAB[BUFR][32];    // fields per slot: S, D, SS, DD (half2)
    __shared__ float  red[2][4];

    const int tid = threadIdx.x;
    const int gx0 = blockIdx.x * TW;
    const int gy0 = blockIdx.y * TH;
    const size_t plane = (size_t)blockIdx.z * (WSZ * (size_t)WSZ);
    const float* Pp = P + plane;
    const float* Tp = T + plane;
    const bool xedge = (blockIdx.x == 0) || (blockIdx.x == GX - 1);

    const float gwf[11] = {W0,W1,W2,W3,W4,W5,W4,W3,W2,W1,W0};
    unsigned gwh[11];   // half2(w,w) bit patterns, wave-uniform -> SGPR
    #pragma unroll
    for (int k = 0; k < 11; ++k)
        gwh[k] = __builtin_amdgcn_readfirstlane(
                     __builtin_bit_cast(unsigned, __float2half2_rn(gwf[k])));

    float mse = 0.f;

    // zero-fill pad rows 42..47 (read by MFMA K-tiles; weights there are 0,
    // but uninitialized LDS could hold Inf/NaN patterns)
    if (tid < 192)
        sAB[IN_H + (tid >> 5)][tid & 31] = make_float4(0.f, 0.f, 0.f, 0.f);

    // ---- stage A (R5-proven): packed-fp16 horizontal 11-tap on S,D,S^2,D^2 ----
    for (int it = tid; it < IN_H * 8; it += 256) {
        const int r  = it >> 3;
        const int q  = it & 7;
        const int gy = gy0 - HALO + r;
        const int cb = gx0 + q * 8 - 8;            // leftmost loaded px (16B aligned)
        const float* prow = Pp + ((long)gy * WSZ + cb);
        const float* trow = Tp + ((long)gy * WSZ + cb);
        const bool rv   = ((unsigned)gy < (unsigned)WSZ);
        const bool mrow = ((unsigned)(r - HALO) < (unsigned)TH);

        const __half2 z = __float2half2_rn(0.f);
        __half2 As[12], Ad[12];

        if (!xedge) {
            if (rv) {
                #pragma unroll
                for (int b = 0; b < 6; ++b) {
                    const float4 pv = *(const float4*)(prow + 4 * b);
                    const float4 tv = *(const float4*)(trow + 4 * b);
                    const float s0 = pv.x + tv.x, s1 = pv.y + tv.y;
                    const float s2 = pv.z + tv.z, s3 = pv.w + tv.w;
                    const float d0 = pv.x - tv.x, d1 = pv.y - tv.y;
                    const float d2 = pv.z - tv.z, d3 = pv.w - tv.w;
                    As[2*b]   = pk(s0, s1); As[2*b+1] = pk(s2, s3);
                    Ad[2*b]   = pk(d0, d1); Ad[2*b+1] = pk(d2, d3);
                    if ((b == 2 || b == 3) && mrow) {
                        mse = fmaf(d0, d0, mse); mse = fmaf(d1, d1, mse);
                        mse = fmaf(d2, d2, mse); mse = fmaf(d3, d3, mse);
                    }
                }
            } else {
                #pragma unroll
                for (int b = 0; b < 12; ++b) { As[b] = z; Ad[b] = z; }
            }
        } else {
            #pragma unroll
            for (int b = 0; b < 6; ++b) {
                const unsigned cc = (unsigned)(cb + 4 * b);
                float4 pv = make_float4(0.f, 0.f, 0.f, 0.f);
                float4 tv = make_float4(0.f, 0.f, 0.f, 0.f);
                if (rv && cc < (unsigned)WSZ) {
                    pv = *(const float4*)(prow + 4 * b);
                    tv = *(const float4*)(trow + 4 * b);
                }
                const float s0 = pv.x + tv.x, s1 = pv.y + tv.y;
                const float s2 = pv.z + tv.z, s3 = pv.w + tv.w;
                const float d0 = pv.x - tv.x, d1 = pv.y - tv.y;
                const float d2 = pv.z - tv.z, d3 = pv.w - tv.w;
                As[2*b]   = pk(s0, s1); As[2*b+1] = pk(s2, s3);
                Ad[2*b]   = pk(d0, d1); Ad[2*b+1] = pk(d2, d3);
                if ((b == 2 || b == 3) && mrow) {
                    mse = fmaf(d0, d0, mse); mse = fmaf(d1, d1, mse);
                    mse = fmaf(d2, d2, mse); mse = fmaf(d3, d3, mse);
                }
            }
        }

        // packed conv: output pair m (=out px 2m,2m+1) needs px[3+2m+k], k=0..10
        __half2 aS[4]  = {z, z, z, z};
        __half2 aD[4]  = {z, z, z, z};
        __half2 aSS[4] = {z, z, z, z};
        __half2 aDD[4] = {z, z, z, z};

        #pragma unroll
        for (int jj = 0; jj <= 16; ++jj) {
            const int j = jj + 3;
            __half2 vs, vd;
            if (j & 1) {
                vs = stagger(As[(j >> 1) + 1], As[j >> 1]);
                vd = stagger(Ad[(j >> 1) + 1], Ad[j >> 1]);
            } else {
                vs = As[j >> 1];
                vd = Ad[j >> 1];
            }
            const __half2 vss = __hmul2(vs, vs);
            const __half2 vdd = __hmul2(vd, vd);
            #pragma unroll
            for (int m = 0; m < 4; ++m) {
                const int k = jj - 2 * m;
                if (k >= 0 && k < 11) {
                    const __half2 w = __builtin_bit_cast(__half2, gwh[k]);
                    aS[m]  = __hfma2(w, vs,  aS[m]);
                    aD[m]  = __hfma2(w, vd,  aD[m]);
                    aSS[m] = __hfma2(w, vss, aSS[m]);
                    aDD[m] = __hfma2(w, vdd, aDD[m]);
                }
            }
        }

        // bank-disperse store: pair pos = 4q+m lives at col pi32(pos)
        #pragma unroll
        for (int m = 0; m < 4; ++m)
            sAB[r][pi32(4 * q + m)] = make_float4(
                __builtin_bit_cast(float, aS[m]),  __builtin_bit_cast(float, aD[m]),
                __builtin_bit_cast(float, aSS[m]), __builtin_bit_cast(float, aDD[m]));
    }
    __syncthreads();

    // ---- stage B: vertical 11-tap via MFMA (R12-verified mapping) ----
    // wave = N-tile n (cols 16n..16n+15); M-tiles m=0,1 (out rows 16m..16m+15);
    // A[ly][k=4t+i] = gw[16c + 4t+i - ly] (ly=lane&15, t=lane>>4).
    // B[k=4t+i][x]  = h[base + 4t+i][16n + (lane&15)].
    const int lane = tid & 63;
    const int nT   = tid >> 6;            // N-tile = wave id
    const int t    = lane >> 4;
    const int colL = lane & 15;
    const int x    = (nT << 4) | colL;    // px col 0..63
    const int p    = x >> 1;              // pair index
    const int colR = pi32(p);             // LDS col (row-independent)
    const unsigned sel = (x & 1) ? 0x07060302u : 0x05040100u;

    // weight fragments for K-tile offset c=0,1: constant-table loads + pkrtz
    f16x4 afrag[2];
    #pragma unroll
    for (int c = 0; c < 2; ++c) {
        float av[4];
        #pragma unroll
        for (int i = 0; i < 4; ++i)
            av[i] = GWPAD[16 * c + 4 * t + i - colL + 16];
        uint2 au;
        au.x = pku(av[0], av[1]);
        au.y = pku(av[2], av[3]);
        afrag[c] = __builtin_bit_cast(f16x4, au);
    }

    f32x4 Dacc[2][4];   // [m][field]
    #pragma unroll
    for (int m = 0; m < 2; ++m)
        #pragma unroll
        for (int f = 0; f < 4; ++f)
            Dacc[m][f] = (f32x4){0.f, 0.f, 0.f, 0.f};

    // 3 distinct K-windows: base 0 (m0c0), 16 (m0c1 = m1c0), 32 (m1c1)
    #pragma unroll
    for (int bi = 0; bi < 3; ++bi) {
        const int base = bi << 4;
        float4 ld[4];
        #pragma unroll
        for (int i = 0; i < 4; ++i)
            ld[i] = sAB[base + 4 * t + i][colR];
        const unsigned* w0 = (const unsigned*)&ld[0];
        const unsigned* w1 = (const unsigned*)&ld[1];
        const unsigned* w2 = (const unsigned*)&ld[2];
        const unsigned* w3 = (const unsigned*)&ld[3];

        f16x4 bf[4];
        #pragma unroll
        for (int f = 0; f < 4; ++f) {
            uint2 bu;
            bu.x = __builtin_amdgcn_perm(w1[f], w0[f], sel);   // k=4t+0,4t+1
            bu.y = __builtin_amdgcn_perm(w3[f], w2[f], sel);   // k=4t+2,4t+3
            bf[f] = __builtin_bit_cast(f16x4, bu);
        }

        if (bi == 0) {
            #pragma unroll
            for (int f = 0; f < 4; ++f)
                Dacc[0][f] = __builtin_amdgcn_mfma_f32_16x16x16f16(
                                 afrag[0], bf[f], Dacc[0][f], 0, 0, 0);
        } else if (bi == 1) {
            #pragma unroll
            for (int f = 0; f < 4; ++f) {
                Dacc[0][f] = __builtin_amdgcn_mfma_f32_16x16x16f16(
                                 afrag[1], bf[f], Dacc[0][f], 0, 0, 0);
                Dacc[1][f] = __builtin_amdgcn_mfma_f32_16x16x16f16(
                                 afrag[0], bf[f], Dacc[1][f], 0, 0, 0);
            }
        } else {
            #pragma unroll
            for (int f = 0; f < 4; ++f)
                Dacc[1][f] = __builtin_amdgcn_mfma_f32_16x16x16f16(
                                 afrag[1], bf[f], Dacc[1][f], 0, 0, 0);
        }
    }

    // ---- SSIM epilogue (fp32), S/D algebra; 8 px per thread ----
    //   2mu12+C1 = 0.5(A^2-B^2)+C1 ; mu1^2+mu2^2+C1 = 0.5(A^2+B^2)+C1
    //   2s12+C2  = 0.5((X-Y)-(A^2-B^2))+C2 ; s1+s2+C2 = 0.5((X+Y)-(A^2+B^2))+C2
    float ssim = 0.f;
    #pragma unroll
    for (int m = 0; m < 2; ++m) {
        #pragma unroll
        for (int j = 0; j < 4; ++j) {
            const float A = Dacc[m][0][j];
            const float B = Dacc[m][1][j];
            const float X = Dacc[m][2][j];
            const float Y = Dacc[m][3][j];
            const float a2 = A * A;
            const float b2 = B * B;
            const float P1 = a2 + b2;
            const float M1 = a2 - b2;
            const float num1 = fmaf(0.5f, M1, SSIM_C1);
            const float den1 = fmaf(0.5f, P1, SSIM_C1);
            const float num2 = fmaf(0.5f, (X - Y) - M1, SSIM_C2);
            const float den2 = fmaf(0.5f, (X + Y) - P1, SSIM_C2);
            ssim = fmaf(num1 * num2, __builtin_amdgcn_rcpf(den1 * den2), ssim);
        }
    }

    // ---- reduction: wave shuffle -> LDS -> 2 plain atomics into a spread slot ----
    #pragma unroll
    for (int off = 32; off > 0; off >>= 1) {
        mse  += __shfl_down(mse, off);
        ssim += __shfl_down(ssim, off);
    }
    const int wid = tid >> 6;
    if ((tid & 63) == 0) { red[0][wid] = mse; red[1][wid] = ssim; }
    __syncthreads();
    if (tid == 0) {
        const float m = red[0][0] + red[0][1] + red[0][2] + red[0][3];
        const float s = red[1][0] + red[1][1] + red[1][2] + red[1][3];
        const int bid  = (blockIdx.z * gridDim.y + blockIdx.y) * gridDim.x + blockIdx.x;
        const int slot = (bid & (NSLOT - 1)) * 16;     // 64B apart -> no line bouncing
        atomicAdd(&ws[slot + 0], m);
        atomicAdd(&ws[slot + 1], s);
    }
}

__global__ void finalize_loss(const float* __restrict__ ws,
                              float* __restrict__ out, float invN) {
    const int t = threadIdx.x;           // 64 threads
    float m = ws[t * 16 + 0];
    float s = ws[t * 16 + 1];
    #pragma unroll
    for (int off = 32; off > 0; off >>= 1) {
        m += __shfl_down(m, off);
        s += __shfl_down(s, off);
    }
    if (t == 0) out[0] = m * invN + 0.01f * (1.f - s * invN);
}

extern "C" void kernel_launch(void* const* d_in, const int* in_sizes, int n_in,
                              void* d_out, int out_size, void* d_ws, size_t ws_size,
                              hipStream_t stream) {
    const float* P = (const float*)d_in[0];
    const float* T = (const float*)d_in[1];
    float* out = (float*)d_out;
    float* ws  = (float*)d_ws;

    const int planes = in_sizes[0] / (WSZ * WSZ);     // 96
    const float invN = 1.f / (float)in_sizes[0];

    (void)hipMemsetAsync(ws, 0, NSLOT * 16 * sizeof(float), stream);
    dim3 grid(GX, GY, planes);
    fused_mse_ssim<<<grid, 256, 0, stream>>>(P, T, ws);
    finalize_loss<<<1, 64, 0, stream>>>(ws, out, invN);
}